// Round 2
// baseline (536.802 us; speedup 1.0000x reference)
//
#include <hip/hip_runtime.h>
#include <stdint.h>

// B=1, L=2048, DIM=1536, H=12, HD=128. Inputs f32, output f32 (verified R6).
// R8: split-K parallelism (stats x8, attn x2), xor-swizzled LDS, single-sweep
// online softmax stats.
// R10: pipeline the two split-MFMA GEMMs (the profiled bottleneck: k_gemm_qkv
// 200us @ MfmaUtil 17.5%, VALUBusy 22%, HBM 9% => pure latency chain).
// Double-buffered LDS + register-staged prefetch: issue next K-tile's global
// loads before compute, split+write to the other buffer after MFMA, one
// barrier per iter. MFMA order (hh,hl,lh) unchanged => bit-identical output.
#define SEQ 2048
#define DIM 1536
#define NH  12
#define HD  128
#define SCALEF 0.08838834764831845f  // 128^-0.5
#define LDP 40  // padded LDS row stride (shorts) for GEMM tiles

typedef __attribute__((ext_vector_type(8))) short short8;
typedef __attribute__((ext_vector_type(4))) float floatx4;

#define MFMA16(a, b, c) __builtin_amdgcn_mfma_f32_16x16x32_bf16((a), (b), (c), 0, 0, 0)

__device__ __forceinline__ void async_cp16(const void* g, void* l) {
  __builtin_amdgcn_global_load_lds(
      (__attribute__((address_space(1))) unsigned int*)(g),
      (__attribute__((address_space(3))) unsigned int*)(l), 16, 0, 0);
}

__device__ __forceinline__ unsigned short f2bf(float f) {
  unsigned int u = __float_as_uint(f);
  u = (u + 0x7fff + ((u >> 16) & 1)) >> 16;  // RNE
  return (unsigned short)u;
}

// Split f32 -> hi (truncated bf16) + lo (RNE bf16 of residual).
__device__ __forceinline__ void split8v(const float* x, short8& h, short8& l) {
#pragma unroll
  for (int e = 0; e < 8; e++) {
    unsigned int u = __float_as_uint(x[e]);
    h[e] = (short)(u >> 16);
    float r = x[e] - __uint_as_float(u & 0xFFFF0000u);
    l[e] = (short)f2bf(r);
  }
}
__device__ __forceinline__ void split8(const float* g, short8& h, short8& l) {
  float4 f0 = *(const float4*)g, f1 = *(const float4*)(g + 4);
  float x[8] = {f0.x, f0.y, f0.z, f0.w, f1.x, f1.y, f1.z, f1.w};
  split8v(x, h, l);
}

__global__ __launch_bounds__(256) void k_fill(float* __restrict__ out, int n,
                                              float val) {
  int i = blockIdx.x * 256 + threadIdx.x;
  if (i < n) out[i] = val;
}

// ---------------------------------------------------------------------------
// K1: QKV projections: C[m,n] = sum_c X[m,c]*W[n,c]. Split-MFMA, 128x128 tile.
// R10: double-buffered LDS + register prefetch of next K-tile.
// ---------------------------------------------------------------------------
__global__ __launch_bounds__(256) void k_gemm_qkv(
    const float* __restrict__ X, const float* __restrict__ Wq,
    const float* __restrict__ Wk, const float* __restrict__ Wv,
    float* __restrict__ qf, float* __restrict__ kf, float* __restrict__ vf,
    unsigned int* __restrict__ scal) {
  __shared__ __align__(16) unsigned short Ah[2][128 * LDP], Al[2][128 * LDP];
  __shared__ __align__(16) unsigned short Bh[2][128 * LDP], Bl[2][128 * LDP];
  int tid = threadIdx.x, z = blockIdx.z;
  const float* W = (z == 0) ? Wq : (z == 1) ? Wk : Wv;
  float* C = (z == 0) ? qf : (z == 1) ? kf : vf;
  int n0 = blockIdx.x * 128, m0 = blockIdx.y * 128;
  int lane = tid & 63, w = tid >> 6;
  int wr = w >> 1, wc = w & 1, lm = lane & 15, q = lane >> 4;

  floatx4 acc[4][4];
#pragma unroll
  for (int i = 0; i < 4; i++)
#pragma unroll
    for (int j = 0; j < 4; j++) acc[i][j] = (floatx4){0.f, 0.f, 0.f, 0.f};

  int rowA = tid >> 2, c8 = tid & 3;
  const float* pA0 = X + (size_t)(m0 + rowA) * DIM + c8 * 8;
  const float* pA1 = pA0 + (size_t)64 * DIM;
  const float* pB0 = W + (size_t)(n0 + rowA) * DIM + c8 * 8;
  const float* pB1 = pB0 + (size_t)64 * DIM;

  // prologue: stage K-tile 0 into buffer 0
  {
    short8 h, l;
    split8(pA0, h, l);
    *(short8*)(&Ah[0][0] + rowA * LDP + c8 * 8) = h;
    *(short8*)(&Al[0][0] + rowA * LDP + c8 * 8) = l;
    split8(pA1, h, l);
    *(short8*)(&Ah[0][0] + (64 + rowA) * LDP + c8 * 8) = h;
    *(short8*)(&Al[0][0] + (64 + rowA) * LDP + c8 * 8) = l;
    split8(pB0, h, l);
    *(short8*)(&Bh[0][0] + rowA * LDP + c8 * 8) = h;
    *(short8*)(&Bl[0][0] + rowA * LDP + c8 * 8) = l;
    split8(pB1, h, l);
    *(short8*)(&Bh[0][0] + (64 + rowA) * LDP + c8 * 8) = h;
    *(short8*)(&Bl[0][0] + (64 + rowA) * LDP + c8 * 8) = l;
  }
  __syncthreads();

  int cur = 0;
  for (int it = 0; it < DIM / 32; ++it) {
    int kn = it * 32 + 32;
    bool more = kn < DIM;
    // issue next-tile global loads early; consumed after MFMA section
    float4 a00, a01, a10, a11, b00, b01, b10, b11;
    if (more) {
      a00 = *(const float4*)(pA0 + kn);
      a01 = *(const float4*)(pA0 + kn + 4);
      a10 = *(const float4*)(pA1 + kn);
      a11 = *(const float4*)(pA1 + kn + 4);
      b00 = *(const float4*)(pB0 + kn);
      b01 = *(const float4*)(pB0 + kn + 4);
      b10 = *(const float4*)(pB1 + kn);
      b11 = *(const float4*)(pB1 + kn + 4);
    }
    // compute current tile from buf[cur]
    const unsigned short* AhC = &Ah[cur][0];
    const unsigned short* AlC = &Al[cur][0];
    const unsigned short* BhC = &Bh[cur][0];
    const unsigned short* BlC = &Bl[cur][0];
    short8 ah[4], al[4], bh[4], bl[4];
#pragma unroll
    for (int i = 0; i < 4; i++) {
      int r = wr * 64 + i * 16 + lm;
      ah[i] = *(const short8*)(AhC + r * LDP + q * 8);
      al[i] = *(const short8*)(AlC + r * LDP + q * 8);
    }
#pragma unroll
    for (int j = 0; j < 4; j++) {
      int r = wc * 64 + j * 16 + lm;
      bh[j] = *(const short8*)(BhC + r * LDP + q * 8);
      bl[j] = *(const short8*)(BlC + r * LDP + q * 8);
    }
#pragma unroll
    for (int i = 0; i < 4; i++)
#pragma unroll
      for (int j = 0; j < 4; j++) {
        acc[i][j] = MFMA16(ah[i], bh[j], acc[i][j]);
        acc[i][j] = MFMA16(ah[i], bl[j], acc[i][j]);
        acc[i][j] = MFMA16(al[i], bh[j], acc[i][j]);
      }
    // split prefetched tile into buf[cur^1]
    if (more) {
      unsigned short* AhN = &Ah[cur ^ 1][0];
      unsigned short* AlN = &Al[cur ^ 1][0];
      unsigned short* BhN = &Bh[cur ^ 1][0];
      unsigned short* BlN = &Bl[cur ^ 1][0];
      short8 h, l;
      {
        float xs[8] = {a00.x, a00.y, a00.z, a00.w, a01.x, a01.y, a01.z, a01.w};
        split8v(xs, h, l);
        *(short8*)(AhN + rowA * LDP + c8 * 8) = h;
        *(short8*)(AlN + rowA * LDP + c8 * 8) = l;
      }
      {
        float xs[8] = {a10.x, a10.y, a10.z, a10.w, a11.x, a11.y, a11.z, a11.w};
        split8v(xs, h, l);
        *(short8*)(AhN + (64 + rowA) * LDP + c8 * 8) = h;
        *(short8*)(AlN + (64 + rowA) * LDP + c8 * 8) = l;
      }
      {
        float xs[8] = {b00.x, b00.y, b00.z, b00.w, b01.x, b01.y, b01.z, b01.w};
        split8v(xs, h, l);
        *(short8*)(BhN + rowA * LDP + c8 * 8) = h;
        *(short8*)(BlN + rowA * LDP + c8 * 8) = l;
      }
      {
        float xs[8] = {b10.x, b10.y, b10.z, b10.w, b11.x, b11.y, b11.z, b11.w};
        split8v(xs, h, l);
        *(short8*)(BhN + (64 + rowA) * LDP + c8 * 8) = h;
        *(short8*)(BlN + (64 + rowA) * LDP + c8 * 8) = l;
      }
      __syncthreads();
    }
    cur ^= 1;
  }
  float am = 0.f;
#pragma unroll
  for (int i = 0; i < 4; i++) {
    int row = m0 + wr * 64 + i * 16 + q * 4;
#pragma unroll
    for (int j = 0; j < 4; j++) {
      int col = n0 + wc * 64 + j * 16 + lm;
#pragma unroll
      for (int r = 0; r < 4; r++) {
        float v = acc[i][j][r];
        C[(size_t)(row + r) * DIM + col] = v;
        am = fmaxf(am, fabsf(v));
      }
    }
  }
#pragma unroll
  for (int mk = 32; mk >= 1; mk >>= 1) am = fmaxf(am, __shfl_xor(am, mk, 64));
  if (lane == 0) atomicMax(&scal[z], __float_as_uint(am));
}

// ---------------------------------------------------------------------------
// K2a: quantize + transpose V -> nvT[h][d][k] (bf16 integer values).
// ---------------------------------------------------------------------------
__global__ __launch_bounds__(256) void k_quant_vT(
    const float* __restrict__ vf, const unsigned int* __restrict__ scal,
    unsigned short* __restrict__ nvT) {
  __shared__ float T[64 * 65];
  int h = blockIdx.z, d0 = blockIdx.y * 64, k0 = blockIdx.x * 64;
  float s = __uint_as_float(scal[2]) / 127.f;
  int t = threadIdx.x;
#pragma unroll
  for (int i = 0; i < 16; i++) {
    int idx = i * 256 + t;
    int r = idx >> 6, c = idx & 63;
    float v = vf[(size_t)(k0 + r) * DIM + h * HD + d0 + c];
    T[r * 65 + c] = fminf(fmaxf(rintf(v / s), -128.f), 127.f);
  }
  __syncthreads();
#pragma unroll
  for (int i = 0; i < 16; i++) {
    int idx = i * 256 + t;
    int d = idx >> 6, r = idx & 63;
    nvT[(size_t)(h * HD + d0 + d) * SEQ + k0 + r] = f2bf(T[r * 65 + d]);
  }
}

// ---------------------------------------------------------------------------
// K2b: quantize q,k -> integer-valued bf16.
// ---------------------------------------------------------------------------
__global__ __launch_bounds__(256) void k_quant_qk(
    const float* __restrict__ qf, const float* __restrict__ kf,
    const unsigned int* __restrict__ scal,
    unsigned short* __restrict__ nq, unsigned short* __restrict__ nk) {
  int z = blockIdx.y;
  const float* src = z ? kf : qf;
  unsigned short* dst = z ? nk : nq;
  float s = __uint_as_float(scal[z]) / 127.f;
  size_t i = ((size_t)blockIdx.x * 256 + threadIdx.x) * 4;
  float4 v = *(const float4*)(src + i);
  ushort4 o;
  o.x = f2bf(fminf(fmaxf(rintf(v.x / s), -128.f), 127.f));
  o.y = f2bf(fminf(fmaxf(rintf(v.y / s), -128.f), 127.f));
  o.z = f2bf(fminf(fmaxf(rintf(v.z / s), -128.f), 127.f));
  o.w = f2bf(fminf(fmaxf(rintf(v.w / s), -128.f), 127.f));
  *(ushort4*)(dst + i) = o;
}

// ---------------------------------------------------------------------------
// K3: partial softmax stats, split-K x8, online per-lane (m,z), swizzled Ks.
// Grid: (8*16, NH). pstats[h][row][chunk][2].
// ---------------------------------------------------------------------------
__global__ __launch_bounds__(256) void k_stats(
    const unsigned short* __restrict__ nq, const unsigned short* __restrict__ nk,
    const unsigned int* __restrict__ scal, float* __restrict__ pstats) {
  __shared__ unsigned short Ks[32 * 128];
  int h = blockIdx.y, tid = threadIdx.x, lane = tid & 63, w = tid >> 6;
  int lm = lane & 15, q = lane >> 4;
  int qb = blockIdx.x & 15, chunk = blockIdx.x >> 4;
  int mb = qb * 128 + w * 32;
  int kbase = chunk * 256;
  float f = (__uint_as_float(scal[0]) / 127.f) *
            (__uint_as_float(scal[1]) / 127.f) * SCALEF;

  short8 aq[2][4];
#pragma unroll
  for (int mi = 0; mi < 2; mi++) {
    const unsigned short* qb_p =
        nq + (size_t)(mb + mi * 16 + lm) * DIM + h * HD + q * 8;
#pragma unroll
    for (int cc = 0; cc < 4; cc++) aq[mi][cc] = *(const short8*)(qb_p + cc * 32);
  }

  float m[2][4], zz[2][4];
#pragma unroll
  for (int mi = 0; mi < 2; mi++)
#pragma unroll
    for (int r = 0; r < 4; r++) { m[mi][r] = -3.0e38f; zz[mi][r] = 0.f; }

  for (int kt = kbase; kt < kbase + 256; kt += 32) {
    __syncthreads();
#pragma unroll
    for (int i = 0; i < 2; i++) {
      int ch = i * 256 + tid;
      int krow = ch >> 4;
      int gcol = (ch & 15) ^ (krow & 7);  // xor-swizzle source column
      async_cp16(nk + (size_t)(kt + krow) * DIM + h * HD + gcol * 8,
                 Ks + ch * 8);
    }
    __syncthreads();
    short8 bk[2][4];
#pragma unroll
    for (int st = 0; st < 2; st++)
#pragma unroll
      for (int cc = 0; cc < 4; cc++) {
        int phys = (cc * 4 + q) ^ (lm & 7);
        bk[st][cc] = *(const short8*)(Ks + (st * 16 + lm) * 128 + phys * 8);
      }
#pragma unroll
    for (int mi = 0; mi < 2; mi++) {
      floatx4 a0 = (floatx4){0.f, 0.f, 0.f, 0.f};
      floatx4 a1 = (floatx4){0.f, 0.f, 0.f, 0.f};
#pragma unroll
      for (int cc = 0; cc < 4; cc++) {
        a0 = MFMA16(aq[mi][cc], bk[0][cc], a0);
        a1 = MFMA16(aq[mi][cc], bk[1][cc], a1);
      }
#pragma unroll
      for (int r = 0; r < 4; r++) {
        float s0 = a0[r] * f, s1 = a1[r] * f;
        float nm = fmaxf(m[mi][r], fmaxf(s0, s1));
        zz[mi][r] = zz[mi][r] * expf(m[mi][r] - nm) + expf(s0 - nm) +
                    expf(s1 - nm);
        m[mi][r] = nm;
      }
    }
  }
  // merge (m,z) across the 16 lanes sharing each row
#pragma unroll
  for (int mk = 1; mk < 16; mk <<= 1)
#pragma unroll
    for (int mi = 0; mi < 2; mi++)
#pragma unroll
      for (int r = 0; r < 4; r++) {
        float om = __shfl_xor(m[mi][r], mk, 64);
        float oz = __shfl_xor(zz[mi][r], mk, 64);
        float nm = fmaxf(m[mi][r], om);
        zz[mi][r] = zz[mi][r] * expf(m[mi][r] - nm) + oz * expf(om - nm);
        m[mi][r] = nm;
      }
  if (lm == 0) {
#pragma unroll
    for (int mi = 0; mi < 2; mi++)
#pragma unroll
      for (int r = 0; r < 4; r++) {
        int row = mb + mi * 16 + q * 4 + r;
        float* p = pstats + (((size_t)h * SEQ + row) * 8 + chunk) * 2;
        p[0] = m[mi][r];
        p[1] = zz[mi][r];
      }
  }
}

// ---------------------------------------------------------------------------
// K3b: merge 8 partial stats per row -> stats[h][row][2], global minZ.
// ---------------------------------------------------------------------------
__global__ __launch_bounds__(256) void k_merge(
    const float* __restrict__ pstats, float* __restrict__ stats,
    unsigned int* __restrict__ minZ) {
  int idx = blockIdx.x * 256 + threadIdx.x;  // h*SEQ + row
  const float* p = pstats + (size_t)idx * 16;
  float M = -3.0e38f;
#pragma unroll
  for (int c = 0; c < 8; c++) M = fmaxf(M, p[c * 2]);
  float Z = 0.f;
#pragma unroll
  for (int c = 0; c < 8; c++) Z += p[c * 2 + 1] * expf(p[c * 2] - M);
  stats[(size_t)idx * 2] = M;
  stats[(size_t)idx * 2 + 1] = Z;
  atomicMin(minZ, __float_as_uint(Z));
}

// ---------------------------------------------------------------------------
// K4: pass 2 — scores, quantize probs, PV. Split-K x2 -> partial O buffers.
// Grid: (2*16, NH). Swizzled Ks and Vs.
// ---------------------------------------------------------------------------
__global__ __launch_bounds__(256) void k_attn(
    const unsigned short* __restrict__ nq, const unsigned short* __restrict__ nk,
    const unsigned short* __restrict__ nvT,
    const unsigned int* __restrict__ scal, const unsigned int* __restrict__ minZ,
    const float* __restrict__ stats, float* __restrict__ attn0,
    float* __restrict__ attn1) {
  __shared__ unsigned short Ks[32 * 128];
  __shared__ unsigned short Vs[128 * 32];
  __shared__ unsigned short Pl[4][2][16 * 40];
  int h = blockIdx.y, tid = threadIdx.x, lane = tid & 63, w = tid >> 6;
  int lm = lane & 15, q = lane >> 4;
  int qb = blockIdx.x & 15, chunk = blockIdx.x >> 4;
  int mb = qb * 128 + w * 32;
  float* attn = chunk ? attn1 : attn0;
  float sv = __uint_as_float(scal[2]) / 127.f;
  float f = (__uint_as_float(scal[0]) / 127.f) *
            (__uint_as_float(scal[1]) / 127.f) * SCALEF;
  float sp = (1.f / __uint_as_float(*minZ)) / 127.f;
  float inv_sp = 1.f / sp;

  short8 aq[2][4];
#pragma unroll
  for (int mi = 0; mi < 2; mi++) {
    const unsigned short* qb_p =
        nq + (size_t)(mb + mi * 16 + lm) * DIM + h * HD + q * 8;
#pragma unroll
    for (int cc = 0; cc < 4; cc++) aq[mi][cc] = *(const short8*)(qb_p + cc * 32);
  }
  float M[2][4], invZ[2][4];
#pragma unroll
  for (int mi = 0; mi < 2; mi++)
#pragma unroll
    for (int r = 0; r < 4; r++) {
      int row = mb + mi * 16 + q * 4 + r;
      M[mi][r] = stats[((size_t)h * SEQ + row) * 2];
      invZ[mi][r] = 1.f / stats[((size_t)h * SEQ + row) * 2 + 1];
    }
  floatx4 accO[2][8];
#pragma unroll
  for (int mi = 0; mi < 2; mi++)
#pragma unroll
    for (int j = 0; j < 8; j++) accO[mi][j] = (floatx4){0.f, 0.f, 0.f, 0.f};

  int kbase = chunk * 1024;
  for (int kt = kbase; kt < kbase + 1024; kt += 32) {
    __syncthreads();
#pragma unroll
    for (int i = 0; i < 2; i++) {
      int ch = i * 256 + tid;
      int krow = ch >> 4;
      int gcol = (ch & 15) ^ (krow & 7);
      async_cp16(nk + (size_t)(kt + krow) * DIM + h * HD + gcol * 8,
                 Ks + ch * 8);
      int d = ch >> 2;
      int vcol = (ch & 3) ^ ((d >> 1) & 3);
      async_cp16(nvT + (size_t)(h * HD + d) * SEQ + kt + vcol * 8,
                 Vs + ch * 8);
    }
    __syncthreads();
    short8 bk[2][4];
#pragma unroll
    for (int st = 0; st < 2; st++)
#pragma unroll
      for (int cc = 0; cc < 4; cc++) {
        int phys = (cc * 4 + q) ^ (lm & 7);
        bk[st][cc] = *(const short8*)(Ks + (st * 16 + lm) * 128 + phys * 8);
      }
#pragma unroll
    for (int mi = 0; mi < 2; mi++)
#pragma unroll
      for (int st = 0; st < 2; st++) {
        floatx4 acc = (floatx4){0.f, 0.f, 0.f, 0.f};
#pragma unroll
        for (int cc = 0; cc < 4; cc++) acc = MFMA16(aq[mi][cc], bk[st][cc], acc);
#pragma unroll
        for (int r = 0; r < 4; r++) {
          float t = expf(acc[r] * f - M[mi][r]);
          float n = rintf(t * invZ[mi][r] * inv_sp);
          n = fminf(n, 127.f);
          Pl[w][mi][(q * 4 + r) * 40 + st * 16 + lm] = f2bf(n);
        }
      }
    __syncthreads();
    short8 ap[2];
#pragma unroll
    for (int mi = 0; mi < 2; mi++)
      ap[mi] = *(const short8*)(&Pl[w][mi][lm * 40 + q * 8]);
#pragma unroll
    for (int j = 0; j < 8; j++) {
      int d = j * 16 + lm;
      int vphys = q ^ ((d >> 1) & 3);
      short8 bv = *(const short8*)(Vs + d * 32 + vphys * 8);
#pragma unroll
      for (int mi = 0; mi < 2; mi++) accO[mi][j] = MFMA16(ap[mi], bv, accO[mi][j]);
    }
  }
  float osc = sp * sv;
#pragma unroll
  for (int mi = 0; mi < 2; mi++)
#pragma unroll
    for (int j = 0; j < 8; j++)
#pragma unroll
      for (int r = 0; r < 4; r++)
        attn[(size_t)(mb + mi * 16 + q * 4 + r) * DIM + h * HD + j * 16 + lm] =
            accO[mi][j][r] * osc;
}

// ---------------------------------------------------------------------------
// K5: out-proj: out[m,n] = sum_c (A0+A1)[m,c]*Wo[n,c] + bo[n]. Split-MFMA.
// R10: same double-buffer + register prefetch pipeline as K1.
// ---------------------------------------------------------------------------
__global__ __launch_bounds__(256) void k_gemm_out(
    const float* __restrict__ A0, const float* __restrict__ A1,
    const float* __restrict__ Wo, const float* __restrict__ bo,
    float* __restrict__ out) {
  __shared__ __align__(16) unsigned short Ah[2][128 * LDP], Al[2][128 * LDP];
  __shared__ __align__(16) unsigned short Bh[2][128 * LDP], Bl[2][128 * LDP];
  int tid = threadIdx.x;
  int n0 = blockIdx.x * 128, m0 = blockIdx.y * 128;
  int lane = tid & 63, w = tid >> 6;
  int wr = w >> 1, wc = w & 1, lm = lane & 15, q = lane >> 4;

  floatx4 acc[4][4];
#pragma unroll
  for (int i = 0; i < 4; i++)
#pragma unroll
    for (int j = 0; j < 4; j++) acc[i][j] = (floatx4){0.f, 0.f, 0.f, 0.f};

  int rowA = tid >> 2, c8 = tid & 3;
  size_t offA0 = (size_t)(m0 + rowA) * DIM + c8 * 8;
  size_t offA1 = offA0 + (size_t)64 * DIM;
  const float* pB0 = Wo + (size_t)(n0 + rowA) * DIM + c8 * 8;
  const float* pB1 = pB0 + (size_t)64 * DIM;

  // prologue: stage K-tile 0 into buffer 0
  {
    short8 h, l;
    {
      float4 x0 = *(const float4*)(A0 + offA0), x1 = *(const float4*)(A0 + offA0 + 4);
      float4 y0 = *(const float4*)(A1 + offA0), y1 = *(const float4*)(A1 + offA0 + 4);
      float xs[8] = {x0.x + y0.x, x0.y + y0.y, x0.z + y0.z, x0.w + y0.w,
                     x1.x + y1.x, x1.y + y1.y, x1.z + y1.z, x1.w + y1.w};
      split8v(xs, h, l);
      *(short8*)(&Ah[0][0] + rowA * LDP + c8 * 8) = h;
      *(short8*)(&Al[0][0] + rowA * LDP + c8 * 8) = l;
    }
    {
      float4 x0 = *(const float4*)(A0 + offA1), x1 = *(const float4*)(A0 + offA1 + 4);
      float4 y0 = *(const float4*)(A1 + offA1), y1 = *(const float4*)(A1 + offA1 + 4);
      float xs[8] = {x0.x + y0.x, x0.y + y0.y, x0.z + y0.z, x0.w + y0.w,
                     x1.x + y1.x, x1.y + y1.y, x1.z + y1.z, x1.w + y1.w};
      split8v(xs, h, l);
      *(short8*)(&Ah[0][0] + (64 + rowA) * LDP + c8 * 8) = h;
      *(short8*)(&Al[0][0] + (64 + rowA) * LDP + c8 * 8) = l;
    }
    split8(pB0, h, l);
    *(short8*)(&Bh[0][0] + rowA * LDP + c8 * 8) = h;
    *(short8*)(&Bl[0][0] + rowA * LDP + c8 * 8) = l;
    split8(pB1, h, l);
    *(short8*)(&Bh[0][0] + (64 + rowA) * LDP + c8 * 8) = h;
    *(short8*)(&Bl[0][0] + (64 + rowA) * LDP + c8 * 8) = l;
  }
  __syncthreads();

  int cur = 0;
  for (int it = 0; it < DIM / 32; ++it) {
    int kn = it * 32 + 32;
    bool more = kn < DIM;
    float4 x00, x01, x10, x11, y00, y01, y10, y11, b00, b01, b10, b11;
    if (more) {
      x00 = *(const float4*)(A0 + offA0 + kn);
      x01 = *(const float4*)(A0 + offA0 + kn + 4);
      y00 = *(const float4*)(A1 + offA0 + kn);
      y01 = *(const float4*)(A1 + offA0 + kn + 4);
      x10 = *(const float4*)(A0 + offA1 + kn);
      x11 = *(const float4*)(A0 + offA1 + kn + 4);
      y10 = *(const float4*)(A1 + offA1 + kn);
      y11 = *(const float4*)(A1 + offA1 + kn + 4);
      b00 = *(const float4*)(pB0 + kn);
      b01 = *(const float4*)(pB0 + kn + 4);
      b10 = *(const float4*)(pB1 + kn);
      b11 = *(const float4*)(pB1 + kn + 4);
    }
    const unsigned short* AhC = &Ah[cur][0];
    const unsigned short* AlC = &Al[cur][0];
    const unsigned short* BhC = &Bh[cur][0];
    const unsigned short* BlC = &Bl[cur][0];
    short8 ah[4], al[4], bh[4], bl[4];
#pragma unroll
    for (int i = 0; i < 4; i++) {
      int r = wr * 64 + i * 16 + lm;
      ah[i] = *(const short8*)(AhC + r * LDP + q * 8);
      al[i] = *(const short8*)(AlC + r * LDP + q * 8);
    }
#pragma unroll
    for (int j = 0; j < 4; j++) {
      int r = wc * 64 + j * 16 + lm;
      bh[j] = *(const short8*)(BhC + r * LDP + q * 8);
      bl[j] = *(const short8*)(BlC + r * LDP + q * 8);
    }
#pragma unroll
    for (int i = 0; i < 4; i++)
#pragma unroll
      for (int j = 0; j < 4; j++) {
        acc[i][j] = MFMA16(ah[i], bh[j], acc[i][j]);
        acc[i][j] = MFMA16(ah[i], bl[j], acc[i][j]);
        acc[i][j] = MFMA16(al[i], bh[j], acc[i][j]);
      }
    if (more) {
      unsigned short* AhN = &Ah[cur ^ 1][0];
      unsigned short* AlN = &Al[cur ^ 1][0];
      unsigned short* BhN = &Bh[cur ^ 1][0];
      unsigned short* BlN = &Bl[cur ^ 1][0];
      short8 h, l;
      {
        float xs[8] = {x00.x + y00.x, x00.y + y00.y, x00.z + y00.z, x00.w + y00.w,
                       x01.x + y01.x, x01.y + y01.y, x01.z + y01.z, x01.w + y01.w};
        split8v(xs, h, l);
        *(short8*)(AhN + rowA * LDP + c8 * 8) = h;
        *(short8*)(AlN + rowA * LDP + c8 * 8) = l;
      }
      {
        float xs[8] = {x10.x + y10.x, x10.y + y10.y, x10.z + y10.z, x10.w + y10.w,
                       x11.x + y11.x, x11.y + y11.y, x11.z + y11.z, x11.w + y11.w};
        split8v(xs, h, l);
        *(short8*)(AhN + (64 + rowA) * LDP + c8 * 8) = h;
        *(short8*)(AlN + (64 + rowA) * LDP + c8 * 8) = l;
      }
      {
        float xs[8] = {b00.x, b00.y, b00.z, b00.w, b01.x, b01.y, b01.z, b01.w};
        split8v(xs, h, l);
        *(short8*)(BhN + rowA * LDP + c8 * 8) = h;
        *(short8*)(BlN + rowA * LDP + c8 * 8) = l;
      }
      {
        float xs[8] = {b10.x, b10.y, b10.z, b10.w, b11.x, b11.y, b11.z, b11.w};
        split8v(xs, h, l);
        *(short8*)(BhN + (64 + rowA) * LDP + c8 * 8) = h;
        *(short8*)(BlN + (64 + rowA) * LDP + c8 * 8) = l;
      }
      __syncthreads();
    }
    cur ^= 1;
  }
#pragma unroll
  for (int j = 0; j < 4; j++) {
    int col = n0 + wc * 64 + j * 16 + lm;
    float bias = bo[col];
#pragma unroll
    for (int i = 0; i < 4; i++) {
      int row = m0 + wr * 64 + i * 16 + q * 4;
#pragma unroll
      for (int r = 0; r < 4; r++)
        out[(size_t)(row + r) * DIM + col] = acc[i][j][r] + bias;
    }
  }
}

// ---------------------------------------------------------------------------
extern "C" void kernel_launch(void* const* d_in, const int* in_sizes, int n_in,
                              void* d_out, int out_size, void* d_ws, size_t ws_size,
                              hipStream_t stream) {
  float* out = (float*)d_out;
  bool sizes_ok = (n_in >= 6) && in_sizes && in_sizes[0] == SEQ * DIM &&
                  in_sizes[1] == DIM * DIM && in_sizes[2] == DIM * DIM &&
                  in_sizes[3] == DIM * DIM && in_sizes[4] == DIM * DIM &&
                  in_sizes[5] == DIM && out_size == SEQ * DIM;
  if (!sizes_ok) {
    k_fill<<<(out_size + 255) / 256, 256, 0, stream>>>(out, out_size, 1.0f);
    return;
  }
  if (ws_size < 50528272) {
    k_fill<<<(out_size + 255) / 256, 256, 0, stream>>>(out, out_size, 2.0f);
    return;
  }

  const float* x  = (const float*)d_in[0];
  const float* Wq = (const float*)d_in[1];
  const float* Wk = (const float*)d_in[2];
  const float* Wv = (const float*)d_in[3];
  const float* Wo = (const float*)d_in[4];
  const float* bo = (const float*)d_in[5];
  char* ws = (char*)d_ws;

  // Workspace layout (peak < 50.53 MB):
  float* qf = (float*)(ws);                                // 12,582,912 B
  float* kf = (float*)(ws + 12582912);                     // 12,582,912 B
  float* vf = (float*)(ws + 25165824);                     // 12,582,912 B
  unsigned short* nq  = (unsigned short*)(ws + 25165824);  // aliases vf (dead)
  float* pstats = (float*)(ws + 31457280);                 // 1,572,864 B
  unsigned short* nvT = (unsigned short*)(ws + 37748736);  // 6,291,456 B
  unsigned short* nk  = (unsigned short*)(ws + 44040192);  // 6,291,456 B
  float* attn0 = qf;                                       // aliases qf (dead)
  float* attn1 = kf;                                       // aliases kf (dead)
  float* stats = (float*)(ws + 50331648);                  // 196,608 B
  unsigned int* scal = (unsigned int*)(ws + 50528256);     // 16 B

  hipMemsetAsync(scal, 0, 12, stream);
  hipMemsetAsync(scal + 3, 0x7f, 4, stream);  // minZ init ~3.39e38

  k_gemm_qkv<<<dim3(DIM / 128, SEQ / 128, 3), 256, 0, stream>>>(
      x, Wq, Wk, Wv, qf, kf, vf, scal);
  k_quant_vT<<<dim3(SEQ / 64, HD / 64, NH), 256, 0, stream>>>(vf, scal, nvT);
  k_quant_qk<<<dim3((SEQ * DIM) / 1024, 2), 256, 0, stream>>>(qf, kf, scal, nq, nk);
  k_stats<<<dim3(8 * 16, NH), 256, 0, stream>>>(nq, nk, scal, pstats);
  k_merge<<<dim3(NH * SEQ / 256), 256, 0, stream>>>(pstats, stats, scal + 3);
  k_attn<<<dim3(2 * 16, NH), 256, 0, stream>>>(nq, nk, nvT, scal, scal + 3,
                                               stats, attn0, attn1);
  k_gemm_out<<<dim3(DIM / 128, SEQ / 128), 256, 0, stream>>>(attn0, attn1, Wo,
                                                             bo, out);
}

// Round 3
// 525.488 us; speedup vs baseline: 1.0215x; 1.0215x over previous
//
#include <hip/hip_runtime.h>
#include <stdint.h>

// B=1, L=2048, DIM=1536, H=12, HD=128. Inputs f32, output f32 (verified R6).
// R8: split-K parallelism (stats x8, attn x2), xor-swizzled LDS, single-sweep
// online softmax stats.
// R10 post-mortem: compiler merged the two if(more) blocks and sank the
// prefetch loads to the split point (VGPR 96 proves regs weren't held) =>
// zero pipeline gain. R11: remove redundant split work instead of reordering:
//  - X is split ONCE (k_split_x) instead of 36x inside k_gemm_qkv; A-staging
//    becomes async global_load_lds (zero VALU) with source-xor swizzle
//    (chunk ^ (row>>1)&3 => 2-way bank access on reads, free).
//  - attn output summed+split ONCE (k_split_o) for k_gemm_out.
//  - W prefetch is straight-line (peeled last iter), issued before the async
//    A-copies so the split waits at vmcnt(4), not 0.
// All arithmetic order unchanged => bit-identical output (absmax 3.428e-3).
#define SEQ 2048
#define DIM 1536
#define NH  12
#define HD  128
#define SCALEF 0.08838834764831845f  // 128^-0.5
#define LDP 40  // padded LDS row stride (shorts) for W tiles

typedef __attribute__((ext_vector_type(8))) short short8;
typedef __attribute__((ext_vector_type(4))) float floatx4;

#define MFMA16(a, b, c) __builtin_amdgcn_mfma_f32_16x16x32_bf16((a), (b), (c), 0, 0, 0)

__device__ __forceinline__ void async_cp16(const void* g, void* l) {
  __builtin_amdgcn_global_load_lds(
      (__attribute__((address_space(1))) unsigned int*)(g),
      (__attribute__((address_space(3))) unsigned int*)(l), 16, 0, 0);
}

__device__ __forceinline__ unsigned short f2bf(float f) {
  unsigned int u = __float_as_uint(f);
  u = (u + 0x7fff + ((u >> 16) & 1)) >> 16;  // RNE
  return (unsigned short)u;
}

// Split f32 -> hi (truncated bf16) + lo (RNE bf16 of residual).
__device__ __forceinline__ void split8v(const float* x, short8& h, short8& l) {
#pragma unroll
  for (int e = 0; e < 8; e++) {
    unsigned int u = __float_as_uint(x[e]);
    h[e] = (short)(u >> 16);
    float r = x[e] - __uint_as_float(u & 0xFFFF0000u);
    l[e] = (short)f2bf(r);
  }
}
__device__ __forceinline__ void split8(const float* g, short8& h, short8& l) {
  float4 f0 = *(const float4*)g, f1 = *(const float4*)(g + 4);
  float x[8] = {f0.x, f0.y, f0.z, f0.w, f1.x, f1.y, f1.z, f1.w};
  split8v(x, h, l);
}

__global__ __launch_bounds__(256) void k_fill(float* __restrict__ out, int n,
                                              float val) {
  int i = blockIdx.x * 256 + threadIdx.x;
  if (i < n) out[i] = val;
}

// ---------------------------------------------------------------------------
// K0a: pre-split X -> Xh, Xl bf16 planes (done once; was 36x inside GEMM).
// ---------------------------------------------------------------------------
__global__ __launch_bounds__(256) void k_split_x(
    const float* __restrict__ X, unsigned short* __restrict__ Xh,
    unsigned short* __restrict__ Xl) {
  size_t i = ((size_t)blockIdx.x * 256 + threadIdx.x) * 8;
  short8 h, l;
  split8(X + i, h, l);
  *(short8*)(Xh + i) = h;
  *(short8*)(Xl + i) = l;
}

// ---------------------------------------------------------------------------
// K0b: pre-sum + split attn output -> Oh, Ol (for k_gemm_out A-side).
// ---------------------------------------------------------------------------
__global__ __launch_bounds__(256) void k_split_o(
    const float* __restrict__ A0, const float* __restrict__ A1,
    unsigned short* __restrict__ Oh, unsigned short* __restrict__ Ol) {
  size_t i = ((size_t)blockIdx.x * 256 + threadIdx.x) * 8;
  float4 x0 = *(const float4*)(A0 + i), x1 = *(const float4*)(A0 + i + 4);
  float4 y0 = *(const float4*)(A1 + i), y1 = *(const float4*)(A1 + i + 4);
  float xs[8] = {x0.x + y0.x, x0.y + y0.y, x0.z + y0.z, x0.w + y0.w,
                 x1.x + y1.x, x1.y + y1.y, x1.z + y1.z, x1.w + y1.w};
  short8 h, l;
  split8v(xs, h, l);
  *(short8*)(Oh + i) = h;
  *(short8*)(Ol + i) = l;
}

// ---------------------------------------------------------------------------
// K1: QKV projections: C[m,n] = sum_c X[m,c]*W[n,c]. Split-MFMA, 128x128 tile.
// A-side: async global_load_lds from pre-split Xh/Xl (xor-swizzled source,
// linear LDS dest). B-side: straight-line reg prefetch + in-loop split.
// ---------------------------------------------------------------------------
__global__ __launch_bounds__(256) void k_gemm_qkv(
    const unsigned short* __restrict__ Xh, const unsigned short* __restrict__ Xl,
    const float* __restrict__ Wq, const float* __restrict__ Wk,
    const float* __restrict__ Wv, float* __restrict__ qf,
    float* __restrict__ kf, float* __restrict__ vf,
    unsigned int* __restrict__ scal) {
  __shared__ __align__(16) unsigned short Ahs[2][128 * 32], Als[2][128 * 32];
  __shared__ __align__(16) unsigned short Bh[2][128 * LDP], Bl[2][128 * LDP];
  int tid = threadIdx.x, z = blockIdx.z;
  const float* W = (z == 0) ? Wq : (z == 1) ? Wk : Wv;
  float* C = (z == 0) ? qf : (z == 1) ? kf : vf;
  int n0 = blockIdx.x * 128, m0 = blockIdx.y * 128;
  int lane = tid & 63, w = tid >> 6;
  int wr = w >> 1, wc = w & 1, lm = lane & 15, q = lane >> 4;

  floatx4 acc[4][4];
#pragma unroll
  for (int i = 0; i < 4; i++)
#pragma unroll
    for (int j = 0; j < 4; j++) acc[i][j] = (floatx4){0.f, 0.f, 0.f, 0.f};

  int rowA = tid >> 2, c8 = tid & 3;
  const float* pB0 = W + (size_t)(n0 + rowA) * DIM + c8 * 8;
  const float* pB1 = pB0 + (size_t)64 * DIM;
  // staging indices for async A copies (per thread: 4 x 16B)
  int sidx0 = tid, sidx1 = 256 + tid;
  int smr0 = sidx0 >> 2, sq0 = (sidx0 & 3) ^ ((smr0 >> 1) & 3);
  int smr1 = sidx1 >> 2, sq1 = (sidx1 & 3) ^ ((smr1 >> 1) & 3);
  size_t gofA0 = (size_t)(m0 + smr0) * DIM + sq0 * 8;
  size_t gofA1 = (size_t)(m0 + smr1) * DIM + sq1 * 8;
  // A-read swizzle: phys chunk = q ^ ((row>>1)&3); row base dep only on lm
  int phA = (q ^ ((lm >> 1) & 3)) * 8;
  int mrbase = wr * 64 + lm;

  // prologue: stage K-tile 0 into buffer 0
  {
    async_cp16(Xh + gofA0, &Ahs[0][0] + sidx0 * 8);
    async_cp16(Xl + gofA0, &Als[0][0] + sidx0 * 8);
    async_cp16(Xh + gofA1, &Ahs[0][0] + sidx1 * 8);
    async_cp16(Xl + gofA1, &Als[0][0] + sidx1 * 8);
    short8 h, l;
    split8(pB0, h, l);
    *(short8*)(&Bh[0][0] + rowA * LDP + c8 * 8) = h;
    *(short8*)(&Bl[0][0] + rowA * LDP + c8 * 8) = l;
    split8(pB1, h, l);
    *(short8*)(&Bh[0][0] + (64 + rowA) * LDP + c8 * 8) = h;
    *(short8*)(&Bl[0][0] + (64 + rowA) * LDP + c8 * 8) = l;
  }
  __syncthreads();

  for (int it = 0; it < 47; ++it) {
    int cur = it & 1, nxt = cur ^ 1;
    int kn = it * 32 + 32;
    // 1. W prefetch (unconditional, straight-line)
    float4 b00 = *(const float4*)(pB0 + kn);
    float4 b01 = *(const float4*)(pB0 + kn + 4);
    float4 b10 = *(const float4*)(pB1 + kn);
    float4 b11 = *(const float4*)(pB1 + kn + 4);
    // 2. async A copies for next tile -> other buffer
    async_cp16(Xh + gofA0 + kn, &Ahs[nxt][0] + sidx0 * 8);
    async_cp16(Xl + gofA0 + kn, &Als[nxt][0] + sidx0 * 8);
    async_cp16(Xh + gofA1 + kn, &Ahs[nxt][0] + sidx1 * 8);
    async_cp16(Xl + gofA1 + kn, &Als[nxt][0] + sidx1 * 8);
    // 3. compute current tile
    short8 ah[4], al[4], bh[4], bl[4];
#pragma unroll
    for (int i = 0; i < 4; i++) {
      int off = (mrbase + i * 16) * 32 + phA;
      ah[i] = *(const short8*)(&Ahs[cur][0] + off);
      al[i] = *(const short8*)(&Als[cur][0] + off);
    }
#pragma unroll
    for (int j = 0; j < 4; j++) {
      int r = wc * 64 + j * 16 + lm;
      bh[j] = *(const short8*)(&Bh[cur][0] + r * LDP + q * 8);
      bl[j] = *(const short8*)(&Bl[cur][0] + r * LDP + q * 8);
    }
#pragma unroll
    for (int i = 0; i < 4; i++)
#pragma unroll
      for (int j = 0; j < 4; j++) {
        acc[i][j] = MFMA16(ah[i], bh[j], acc[i][j]);
        acc[i][j] = MFMA16(ah[i], bl[j], acc[i][j]);
        acc[i][j] = MFMA16(al[i], bh[j], acc[i][j]);
      }
    // 4. split W regs into other buffer (waits vmcnt(4): W done, asyncs fly)
    {
      short8 h, l;
      {
        float xs[8] = {b00.x, b00.y, b00.z, b00.w, b01.x, b01.y, b01.z, b01.w};
        split8v(xs, h, l);
        *(short8*)(&Bh[nxt][0] + rowA * LDP + c8 * 8) = h;
        *(short8*)(&Bl[nxt][0] + rowA * LDP + c8 * 8) = l;
      }
      {
        float xs[8] = {b10.x, b10.y, b10.z, b10.w, b11.x, b11.y, b11.z, b11.w};
        split8v(xs, h, l);
        *(short8*)(&Bh[nxt][0] + (64 + rowA) * LDP + c8 * 8) = h;
        *(short8*)(&Bl[nxt][0] + (64 + rowA) * LDP + c8 * 8) = l;
      }
    }
    __syncthreads();
  }
  // epilogue: tile 47 from buffer 1
  {
    short8 ah[4], al[4], bh[4], bl[4];
#pragma unroll
    for (int i = 0; i < 4; i++) {
      int off = (mrbase + i * 16) * 32 + phA;
      ah[i] = *(const short8*)(&Ahs[1][0] + off);
      al[i] = *(const short8*)(&Als[1][0] + off);
    }
#pragma unroll
    for (int j = 0; j < 4; j++) {
      int r = wc * 64 + j * 16 + lm;
      bh[j] = *(const short8*)(&Bh[1][0] + r * LDP + q * 8);
      bl[j] = *(const short8*)(&Bl[1][0] + r * LDP + q * 8);
    }
#pragma unroll
    for (int i = 0; i < 4; i++)
#pragma unroll
      for (int j = 0; j < 4; j++) {
        acc[i][j] = MFMA16(ah[i], bh[j], acc[i][j]);
        acc[i][j] = MFMA16(ah[i], bl[j], acc[i][j]);
        acc[i][j] = MFMA16(al[i], bh[j], acc[i][j]);
      }
  }
  float am = 0.f;
#pragma unroll
  for (int i = 0; i < 4; i++) {
    int row = m0 + wr * 64 + i * 16 + q * 4;
#pragma unroll
    for (int j = 0; j < 4; j++) {
      int col = n0 + wc * 64 + j * 16 + lm;
#pragma unroll
      for (int r = 0; r < 4; r++) {
        float v = acc[i][j][r];
        C[(size_t)(row + r) * DIM + col] = v;
        am = fmaxf(am, fabsf(v));
      }
    }
  }
#pragma unroll
  for (int mk = 32; mk >= 1; mk >>= 1) am = fmaxf(am, __shfl_xor(am, mk, 64));
  if (lane == 0) atomicMax(&scal[z], __float_as_uint(am));
}

// ---------------------------------------------------------------------------
// K2a: quantize + transpose V -> nvT[h][d][k] (bf16 integer values).
// ---------------------------------------------------------------------------
__global__ __launch_bounds__(256) void k_quant_vT(
    const float* __restrict__ vf, const unsigned int* __restrict__ scal,
    unsigned short* __restrict__ nvT) {
  __shared__ float T[64 * 65];
  int h = blockIdx.z, d0 = blockIdx.y * 64, k0 = blockIdx.x * 64;
  float s = __uint_as_float(scal[2]) / 127.f;
  int t = threadIdx.x;
#pragma unroll
  for (int i = 0; i < 16; i++) {
    int idx = i * 256 + t;
    int r = idx >> 6, c = idx & 63;
    float v = vf[(size_t)(k0 + r) * DIM + h * HD + d0 + c];
    T[r * 65 + c] = fminf(fmaxf(rintf(v / s), -128.f), 127.f);
  }
  __syncthreads();
#pragma unroll
  for (int i = 0; i < 16; i++) {
    int idx = i * 256 + t;
    int d = idx >> 6, r = idx & 63;
    nvT[(size_t)(h * HD + d0 + d) * SEQ + k0 + r] = f2bf(T[r * 65 + d]);
  }
}

// ---------------------------------------------------------------------------
// K2b: quantize q,k -> integer-valued bf16.
// ---------------------------------------------------------------------------
__global__ __launch_bounds__(256) void k_quant_qk(
    const float* __restrict__ qf, const float* __restrict__ kf,
    const unsigned int* __restrict__ scal,
    unsigned short* __restrict__ nq, unsigned short* __restrict__ nk) {
  int z = blockIdx.y;
  const float* src = z ? kf : qf;
  unsigned short* dst = z ? nk : nq;
  float s = __uint_as_float(scal[z]) / 127.f;
  size_t i = ((size_t)blockIdx.x * 256 + threadIdx.x) * 4;
  float4 v = *(const float4*)(src + i);
  ushort4 o;
  o.x = f2bf(fminf(fmaxf(rintf(v.x / s), -128.f), 127.f));
  o.y = f2bf(fminf(fmaxf(rintf(v.y / s), -128.f), 127.f));
  o.z = f2bf(fminf(fmaxf(rintf(v.z / s), -128.f), 127.f));
  o.w = f2bf(fminf(fmaxf(rintf(v.w / s), -128.f), 127.f));
  *(ushort4*)(dst + i) = o;
}

// ---------------------------------------------------------------------------
// K3: partial softmax stats, split-K x8, online per-lane (m,z), swizzled Ks.
// Grid: (8*16, NH). pstats[h][row][chunk][2].
// ---------------------------------------------------------------------------
__global__ __launch_bounds__(256) void k_stats(
    const unsigned short* __restrict__ nq, const unsigned short* __restrict__ nk,
    const unsigned int* __restrict__ scal, float* __restrict__ pstats) {
  __shared__ unsigned short Ks[32 * 128];
  int h = blockIdx.y, tid = threadIdx.x, lane = tid & 63, w = tid >> 6;
  int lm = lane & 15, q = lane >> 4;
  int qb = blockIdx.x & 15, chunk = blockIdx.x >> 4;
  int mb = qb * 128 + w * 32;
  int kbase = chunk * 256;
  float f = (__uint_as_float(scal[0]) / 127.f) *
            (__uint_as_float(scal[1]) / 127.f) * SCALEF;

  short8 aq[2][4];
#pragma unroll
  for (int mi = 0; mi < 2; mi++) {
    const unsigned short* qb_p =
        nq + (size_t)(mb + mi * 16 + lm) * DIM + h * HD + q * 8;
#pragma unroll
    for (int cc = 0; cc < 4; cc++) aq[mi][cc] = *(const short8*)(qb_p + cc * 32);
  }

  float m[2][4], zz[2][4];
#pragma unroll
  for (int mi = 0; mi < 2; mi++)
#pragma unroll
    for (int r = 0; r < 4; r++) { m[mi][r] = -3.0e38f; zz[mi][r] = 0.f; }

  for (int kt = kbase; kt < kbase + 256; kt += 32) {
    __syncthreads();
#pragma unroll
    for (int i = 0; i < 2; i++) {
      int ch = i * 256 + tid;
      int krow = ch >> 4;
      int gcol = (ch & 15) ^ (krow & 7);  // xor-swizzle source column
      async_cp16(nk + (size_t)(kt + krow) * DIM + h * HD + gcol * 8,
                 Ks + ch * 8);
    }
    __syncthreads();
    short8 bk[2][4];
#pragma unroll
    for (int st = 0; st < 2; st++)
#pragma unroll
      for (int cc = 0; cc < 4; cc++) {
        int phys = (cc * 4 + q) ^ (lm & 7);
        bk[st][cc] = *(const short8*)(Ks + (st * 16 + lm) * 128 + phys * 8);
      }
#pragma unroll
    for (int mi = 0; mi < 2; mi++) {
      floatx4 a0 = (floatx4){0.f, 0.f, 0.f, 0.f};
      floatx4 a1 = (floatx4){0.f, 0.f, 0.f, 0.f};
#pragma unroll
      for (int cc = 0; cc < 4; cc++) {
        a0 = MFMA16(aq[mi][cc], bk[0][cc], a0);
        a1 = MFMA16(aq[mi][cc], bk[1][cc], a1);
      }
#pragma unroll
      for (int r = 0; r < 4; r++) {
        float s0 = a0[r] * f, s1 = a1[r] * f;
        float nm = fmaxf(m[mi][r], fmaxf(s0, s1));
        zz[mi][r] = zz[mi][r] * expf(m[mi][r] - nm) + expf(s0 - nm) +
                    expf(s1 - nm);
        m[mi][r] = nm;
      }
    }
  }
  // merge (m,z) across the 16 lanes sharing each row
#pragma unroll
  for (int mk = 1; mk < 16; mk <<= 1)
#pragma unroll
    for (int mi = 0; mi < 2; mi++)
#pragma unroll
      for (int r = 0; r < 4; r++) {
        float om = __shfl_xor(m[mi][r], mk, 64);
        float oz = __shfl_xor(zz[mi][r], mk, 64);
        float nm = fmaxf(m[mi][r], om);
        zz[mi][r] = zz[mi][r] * expf(m[mi][r] - nm) + oz * expf(om - nm);
        m[mi][r] = nm;
      }
  if (lm == 0) {
#pragma unroll
    for (int mi = 0; mi < 2; mi++)
#pragma unroll
      for (int r = 0; r < 4; r++) {
        int row = mb + mi * 16 + q * 4 + r;
        float* p = pstats + (((size_t)h * SEQ + row) * 8 + chunk) * 2;
        p[0] = m[mi][r];
        p[1] = zz[mi][r];
      }
  }
}

// ---------------------------------------------------------------------------
// K3b: merge 8 partial stats per row -> stats[h][row][2], global minZ.
// ---------------------------------------------------------------------------
__global__ __launch_bounds__(256) void k_merge(
    const float* __restrict__ pstats, float* __restrict__ stats,
    unsigned int* __restrict__ minZ) {
  int idx = blockIdx.x * 256 + threadIdx.x;  // h*SEQ + row
  const float* p = pstats + (size_t)idx * 16;
  float M = -3.0e38f;
#pragma unroll
  for (int c = 0; c < 8; c++) M = fmaxf(M, p[c * 2]);
  float Z = 0.f;
#pragma unroll
  for (int c = 0; c < 8; c++) Z += p[c * 2 + 1] * expf(p[c * 2] - M);
  stats[(size_t)idx * 2] = M;
  stats[(size_t)idx * 2 + 1] = Z;
  atomicMin(minZ, __float_as_uint(Z));
}

// ---------------------------------------------------------------------------
// K4: pass 2 — scores, quantize probs, PV. Split-K x2 -> partial O buffers.
// Grid: (2*16, NH). Swizzled Ks and Vs.
// ---------------------------------------------------------------------------
__global__ __launch_bounds__(256) void k_attn(
    const unsigned short* __restrict__ nq, const unsigned short* __restrict__ nk,
    const unsigned short* __restrict__ nvT,
    const unsigned int* __restrict__ scal, const unsigned int* __restrict__ minZ,
    const float* __restrict__ stats, float* __restrict__ attn0,
    float* __restrict__ attn1) {
  __shared__ unsigned short Ks[32 * 128];
  __shared__ unsigned short Vs[128 * 32];
  __shared__ unsigned short Pl[4][2][16 * 40];
  int h = blockIdx.y, tid = threadIdx.x, lane = tid & 63, w = tid >> 6;
  int lm = lane & 15, q = lane >> 4;
  int qb = blockIdx.x & 15, chunk = blockIdx.x >> 4;
  int mb = qb * 128 + w * 32;
  float* attn = chunk ? attn1 : attn0;
  float sv = __uint_as_float(scal[2]) / 127.f;
  float f = (__uint_as_float(scal[0]) / 127.f) *
            (__uint_as_float(scal[1]) / 127.f) * SCALEF;
  float sp = (1.f / __uint_as_float(*minZ)) / 127.f;
  float inv_sp = 1.f / sp;

  short8 aq[2][4];
#pragma unroll
  for (int mi = 0; mi < 2; mi++) {
    const unsigned short* qb_p =
        nq + (size_t)(mb + mi * 16 + lm) * DIM + h * HD + q * 8;
#pragma unroll
    for (int cc = 0; cc < 4; cc++) aq[mi][cc] = *(const short8*)(qb_p + cc * 32);
  }
  float M[2][4], invZ[2][4];
#pragma unroll
  for (int mi = 0; mi < 2; mi++)
#pragma unroll
    for (int r = 0; r < 4; r++) {
      int row = mb + mi * 16 + q * 4 + r;
      M[mi][r] = stats[((size_t)h * SEQ + row) * 2];
      invZ[mi][r] = 1.f / stats[((size_t)h * SEQ + row) * 2 + 1];
    }
  floatx4 accO[2][8];
#pragma unroll
  for (int mi = 0; mi < 2; mi++)
#pragma unroll
    for (int j = 0; j < 8; j++) accO[mi][j] = (floatx4){0.f, 0.f, 0.f, 0.f};

  int kbase = chunk * 1024;
  for (int kt = kbase; kt < kbase + 1024; kt += 32) {
    __syncthreads();
#pragma unroll
    for (int i = 0; i < 2; i++) {
      int ch = i * 256 + tid;
      int krow = ch >> 4;
      int gcol = (ch & 15) ^ (krow & 7);
      async_cp16(nk + (size_t)(kt + krow) * DIM + h * HD + gcol * 8,
                 Ks + ch * 8);
      int d = ch >> 2;
      int vcol = (ch & 3) ^ ((d >> 1) & 3);
      async_cp16(nvT + (size_t)(h * HD + d) * SEQ + kt + vcol * 8,
                 Vs + ch * 8);
    }
    __syncthreads();
    short8 bk[2][4];
#pragma unroll
    for (int st = 0; st < 2; st++)
#pragma unroll
      for (int cc = 0; cc < 4; cc++) {
        int phys = (cc * 4 + q) ^ (lm & 7);
        bk[st][cc] = *(const short8*)(Ks + (st * 16 + lm) * 128 + phys * 8);
      }
#pragma unroll
    for (int mi = 0; mi < 2; mi++)
#pragma unroll
      for (int st = 0; st < 2; st++) {
        floatx4 acc = (floatx4){0.f, 0.f, 0.f, 0.f};
#pragma unroll
        for (int cc = 0; cc < 4; cc++) acc = MFMA16(aq[mi][cc], bk[st][cc], acc);
#pragma unroll
        for (int r = 0; r < 4; r++) {
          float t = expf(acc[r] * f - M[mi][r]);
          float n = rintf(t * invZ[mi][r] * inv_sp);
          n = fminf(n, 127.f);
          Pl[w][mi][(q * 4 + r) * 40 + st * 16 + lm] = f2bf(n);
        }
      }
    __syncthreads();
    short8 ap[2];
#pragma unroll
    for (int mi = 0; mi < 2; mi++)
      ap[mi] = *(const short8*)(&Pl[w][mi][lm * 40 + q * 8]);
#pragma unroll
    for (int j = 0; j < 8; j++) {
      int d = j * 16 + lm;
      int vphys = q ^ ((d >> 1) & 3);
      short8 bv = *(const short8*)(Vs + d * 32 + vphys * 8);
#pragma unroll
      for (int mi = 0; mi < 2; mi++) accO[mi][j] = MFMA16(ap[mi], bv, accO[mi][j]);
    }
  }
  float osc = sp * sv;
#pragma unroll
  for (int mi = 0; mi < 2; mi++)
#pragma unroll
    for (int j = 0; j < 8; j++)
#pragma unroll
      for (int r = 0; r < 4; r++)
        attn[(size_t)(mb + mi * 16 + q * 4 + r) * DIM + h * HD + j * 16 + lm] =
            accO[mi][j][r] * osc;
}

// ---------------------------------------------------------------------------
// K5: out-proj: out[m,n] = sum_c O[m,c]*Wo[n,c] + bo[n]. Split-MFMA.
// A-side pre-split (Oh/Ol) via k_split_o; same pipeline as K1.
// ---------------------------------------------------------------------------
__global__ __launch_bounds__(256) void k_gemm_out(
    const unsigned short* __restrict__ Oh, const unsigned short* __restrict__ Ol,
    const float* __restrict__ Wo, const float* __restrict__ bo,
    float* __restrict__ out) {
  __shared__ __align__(16) unsigned short Ahs[2][128 * 32], Als[2][128 * 32];
  __shared__ __align__(16) unsigned short Bh[2][128 * LDP], Bl[2][128 * LDP];
  int tid = threadIdx.x;
  int n0 = blockIdx.x * 128, m0 = blockIdx.y * 128;
  int lane = tid & 63, w = tid >> 6;
  int wr = w >> 1, wc = w & 1, lm = lane & 15, q = lane >> 4;

  floatx4 acc[4][4];
#pragma unroll
  for (int i = 0; i < 4; i++)
#pragma unroll
    for (int j = 0; j < 4; j++) acc[i][j] = (floatx4){0.f, 0.f, 0.f, 0.f};

  int rowA = tid >> 2, c8 = tid & 3;
  const float* pB0 = Wo + (size_t)(n0 + rowA) * DIM + c8 * 8;
  const float* pB1 = pB0 + (size_t)64 * DIM;
  int sidx0 = tid, sidx1 = 256 + tid;
  int smr0 = sidx0 >> 2, sq0 = (sidx0 & 3) ^ ((smr0 >> 1) & 3);
  int smr1 = sidx1 >> 2, sq1 = (sidx1 & 3) ^ ((smr1 >> 1) & 3);
  size_t gofA0 = (size_t)(m0 + smr0) * DIM + sq0 * 8;
  size_t gofA1 = (size_t)(m0 + smr1) * DIM + sq1 * 8;
  int phA = (q ^ ((lm >> 1) & 3)) * 8;
  int mrbase = wr * 64 + lm;

  // prologue
  {
    async_cp16(Oh + gofA0, &Ahs[0][0] + sidx0 * 8);
    async_cp16(Ol + gofA0, &Als[0][0] + sidx0 * 8);
    async_cp16(Oh + gofA1, &Ahs[0][0] + sidx1 * 8);
    async_cp16(Ol + gofA1, &Als[0][0] + sidx1 * 8);
    short8 h, l;
    split8(pB0, h, l);
    *(short8*)(&Bh[0][0] + rowA * LDP + c8 * 8) = h;
    *(short8*)(&Bl[0][0] + rowA * LDP + c8 * 8) = l;
    split8(pB1, h, l);
    *(short8*)(&Bh[0][0] + (64 + rowA) * LDP + c8 * 8) = h;
    *(short8*)(&Bl[0][0] + (64 + rowA) * LDP + c8 * 8) = l;
  }
  __syncthreads();

  for (int it = 0; it < 47; ++it) {
    int cur = it & 1, nxt = cur ^ 1;
    int kn = it * 32 + 32;
    float4 b00 = *(const float4*)(pB0 + kn);
    float4 b01 = *(const float4*)(pB0 + kn + 4);
    float4 b10 = *(const float4*)(pB1 + kn);
    float4 b11 = *(const float4*)(pB1 + kn + 4);
    async_cp16(Oh + gofA0 + kn, &Ahs[nxt][0] + sidx0 * 8);
    async_cp16(Ol + gofA0 + kn, &Als[nxt][0] + sidx0 * 8);
    async_cp16(Oh + gofA1 + kn, &Ahs[nxt][0] + sidx1 * 8);
    async_cp16(Ol + gofA1 + kn, &Als[nxt][0] + sidx1 * 8);
    short8 ah[4], al[4], bh[4], bl[4];
#pragma unroll
    for (int i = 0; i < 4; i++) {
      int off = (mrbase + i * 16) * 32 + phA;
      ah[i] = *(const short8*)(&Ahs[cur][0] + off);
      al[i] = *(const short8*)(&Als[cur][0] + off);
    }
#pragma unroll
    for (int j = 0; j < 4; j++) {
      int r = wc * 64 + j * 16 + lm;
      bh[j] = *(const short8*)(&Bh[cur][0] + r * LDP + q * 8);
      bl[j] = *(const short8*)(&Bl[cur][0] + r * LDP + q * 8);
    }
#pragma unroll
    for (int i = 0; i < 4; i++)
#pragma unroll
      for (int j = 0; j < 4; j++) {
        acc[i][j] = MFMA16(ah[i], bh[j], acc[i][j]);
        acc[i][j] = MFMA16(ah[i], bl[j], acc[i][j]);
        acc[i][j] = MFMA16(al[i], bh[j], acc[i][j]);
      }
    {
      short8 h, l;
      {
        float xs[8] = {b00.x, b00.y, b00.z, b00.w, b01.x, b01.y, b01.z, b01.w};
        split8v(xs, h, l);
        *(short8*)(&Bh[nxt][0] + rowA * LDP + c8 * 8) = h;
        *(short8*)(&Bl[nxt][0] + rowA * LDP + c8 * 8) = l;
      }
      {
        float xs[8] = {b10.x, b10.y, b10.z, b10.w, b11.x, b11.y, b11.z, b11.w};
        split8v(xs, h, l);
        *(short8*)(&Bh[nxt][0] + (64 + rowA) * LDP + c8 * 8) = h;
        *(short8*)(&Bl[nxt][0] + (64 + rowA) * LDP + c8 * 8) = l;
      }
    }
    __syncthreads();
  }
  {
    short8 ah[4], al[4], bh[4], bl[4];
#pragma unroll
    for (int i = 0; i < 4; i++) {
      int off = (mrbase + i * 16) * 32 + phA;
      ah[i] = *(const short8*)(&Ahs[1][0] + off);
      al[i] = *(const short8*)(&Als[1][0] + off);
    }
#pragma unroll
    for (int j = 0; j < 4; j++) {
      int r = wc * 64 + j * 16 + lm;
      bh[j] = *(const short8*)(&Bh[1][0] + r * LDP + q * 8);
      bl[j] = *(const short8*)(&Bl[1][0] + r * LDP + q * 8);
    }
#pragma unroll
    for (int i = 0; i < 4; i++)
#pragma unroll
      for (int j = 0; j < 4; j++) {
        acc[i][j] = MFMA16(ah[i], bh[j], acc[i][j]);
        acc[i][j] = MFMA16(ah[i], bl[j], acc[i][j]);
        acc[i][j] = MFMA16(al[i], bh[j], acc[i][j]);
      }
  }
#pragma unroll
  for (int j = 0; j < 4; j++) {
    int col = n0 + wc * 64 + j * 16 + lm;
    float bias = bo[col];
#pragma unroll
    for (int i = 0; i < 4; i++) {
      int row = m0 + wr * 64 + i * 16 + q * 4;
#pragma unroll
      for (int r = 0; r < 4; r++)
        out[(size_t)(row + r) * DIM + col] = acc[i][j][r] + bias;
    }
  }
}

// ---------------------------------------------------------------------------
extern "C" void kernel_launch(void* const* d_in, const int* in_sizes, int n_in,
                              void* d_out, int out_size, void* d_ws, size_t ws_size,
                              hipStream_t stream) {
  float* out = (float*)d_out;
  bool sizes_ok = (n_in >= 6) && in_sizes && in_sizes[0] == SEQ * DIM &&
                  in_sizes[1] == DIM * DIM && in_sizes[2] == DIM * DIM &&
                  in_sizes[3] == DIM * DIM && in_sizes[4] == DIM * DIM &&
                  in_sizes[5] == DIM && out_size == SEQ * DIM;
  if (!sizes_ok) {
    k_fill<<<(out_size + 255) / 256, 256, 0, stream>>>(out, out_size, 1.0f);
    return;
  }
  if (ws_size < 50528272) {
    k_fill<<<(out_size + 255) / 256, 256, 0, stream>>>(out, out_size, 2.0f);
    return;
  }

  const float* x  = (const float*)d_in[0];
  const float* Wq = (const float*)d_in[1];
  const float* Wk = (const float*)d_in[2];
  const float* Wv = (const float*)d_in[3];
  const float* Wo = (const float*)d_in[4];
  const float* bo = (const float*)d_in[5];
  char* ws = (char*)d_ws;

  // Workspace layout (peak < 50.53 MB):
  float* qf = (float*)(ws);                                // 12,582,912 B
  float* kf = (float*)(ws + 12582912);                     // 12,582,912 B
  float* vf = (float*)(ws + 25165824);                     // 12,582,912 B
  unsigned short* nq  = (unsigned short*)(ws + 25165824);  // aliases vf (dead)
  float* pstats = (float*)(ws + 31457280);                 // 1,572,864 B
  unsigned short* nvT = (unsigned short*)(ws + 37748736);  // 6,291,456 B
  unsigned short* nk  = (unsigned short*)(ws + 44040192);  // 6,291,456 B
  // X-split planes live in the nvT/nk slots until k_quant_vT/k_quant_qk run:
  unsigned short* Xh = nvT;   // dead after k_gemm_qkv
  unsigned short* Xl = nk;    // dead after k_gemm_qkv
  // attn-output split planes reuse the same slots after k_attn:
  unsigned short* Oh = nvT;   // written by k_split_o (nvT dead after k_attn)
  unsigned short* Ol = nk;    // written by k_split_o (nk dead after k_attn)
  float* attn0 = qf;                                       // aliases qf (dead)
  float* attn1 = kf;                                       // aliases kf (dead)
  float* stats = (float*)(ws + 50331648);                  // 196,608 B
  unsigned int* scal = (unsigned int*)(ws + 50528256);     // 16 B

  hipMemsetAsync(scal, 0, 12, stream);
  hipMemsetAsync(scal + 3, 0x7f, 4, stream);  // minZ init ~3.39e38

  k_split_x<<<dim3(SEQ * DIM / 2048), 256, 0, stream>>>(x, Xh, Xl);
  k_gemm_qkv<<<dim3(DIM / 128, SEQ / 128, 3), 256, 0, stream>>>(
      Xh, Xl, Wq, Wk, Wv, qf, kf, vf, scal);
  k_quant_vT<<<dim3(SEQ / 64, HD / 64, NH), 256, 0, stream>>>(vf, scal, nvT);
  k_quant_qk<<<dim3((SEQ * DIM) / 1024, 2), 256, 0, stream>>>(qf, kf, scal, nq, nk);
  k_stats<<<dim3(8 * 16, NH), 256, 0, stream>>>(nq, nk, scal, pstats);
  k_merge<<<dim3(NH * SEQ / 256), 256, 0, stream>>>(pstats, stats, scal + 3);
  k_attn<<<dim3(2 * 16, NH), 256, 0, stream>>>(nq, nk, nvT, scal, scal + 3,
                                               stats, attn0, attn1);
  k_split_o<<<dim3(SEQ * DIM / 2048), 256, 0, stream>>>(attn0, attn1, Oh, Ol);
  k_gemm_out<<<dim3(DIM / 128, SEQ / 128), 256, 0, stream>>>(Oh, Ol, Wo, bo, out);
}